// Round 8
// baseline (184.802 us; speedup 1.0000x reference)
//
#include <hip/hip_runtime.h>
#include <math.h>

#define KQ   32768
#define CC   100
#define BB   1024
#define DD   128
#define NTOT (BB + KQ)        // 33792
#define CB_CENT 1056
#define NCB  1060             // 32-row blocks in X2
#define NHIST 33              // histogram blocks
#define NCG2 132              // branch-2 col groups (8 cb each)

#define INV_T  14.285714285714286f
#define K2E    20.609929f     // INV_T * log2(e)
#define ALPHA  0.05f
#define EPSV   1e-12f

typedef __attribute__((ext_vector_type(8)))  short          short8;
typedef __attribute__((ext_vector_type(8)))  unsigned short ushort8;
typedef __attribute__((ext_vector_type(16))) float          float16;

__device__ __forceinline__ unsigned short f2bf_rne(float f) {
    unsigned int u = __float_as_uint(f);
    return (unsigned short)((u + 0x7FFFu + ((u >> 16) & 1u)) >> 16);
}

// X2 layout per 32-row block cb (8192 B): [ks 0..7][lane 0..63][16 B]
// element (row r, k): cb=r>>5, ks=k>>4, lane=(r&31)+32*((k>>3)&1), j=k&7
// == 32x32x16 MFMA A/B operand layout (verified R2-R7).

// ---------------- prep: direct convert+tile (no LDS) + parallel histogram ----------------
__global__ __launch_bounds__(256) void prep_k(const float* __restrict__ feats,
                                              const float* __restrict__ centers,
                                              const int* __restrict__ labels,
                                              unsigned short* __restrict__ X2,
                                              int* __restrict__ cntAll,
                                              int* __restrict__ cntBatch) {
    const int b = blockIdx.x, t = threadIdx.x;
    if (b >= NCB) {  // histogram: LDS-local then one global atomic per bin
        __shared__ int hA[CC], hB[CC];
        if (t < CC) { hA[t] = 0; hB[t] = 0; }
        __syncthreads();
        const int base = (b - NCB) * 1024;
#pragma unroll
        for (int q = 0; q < 4; ++q) {
            int idx = base + q * 256 + t;
            int l = labels[idx];
            atomicAdd(&hA[l], 1);
            if (idx < BB) atomicAdd(&hB[l], 1);
        }
        __syncthreads();
        if (t < CC) {
            if (hA[t]) atomicAdd(&cntAll[t], hA[t]);
            if (hB[t]) atomicAdd(&cntBatch[t], hB[t]);
        }
        return;
    }
    // each thread fills 2 of the 512 16-B output slots; writes perfectly coalesced
#pragma unroll
    for (int s = 0; s < 2; ++s) {
        const int slot = s * 256 + t;          // 0..511
        const int ks = slot >> 6, lane = slot & 63;
        const int row = lane & 31, h = lane >> 5;
        const int r = b * 32 + row;
        float v[8];
        if (r < NTOT) {
            const float4* p = (const float4*)&feats[(size_t)r * DD + ks * 16 + h * 8];
            float4 q0 = p[0], q1 = p[1];
            v[0]=q0.x; v[1]=q0.y; v[2]=q0.z; v[3]=q0.w;
            v[4]=q1.x; v[5]=q1.y; v[6]=q1.z; v[7]=q1.w;
        } else if (r < NTOT + CC) {
            const float4* p = (const float4*)&centers[(size_t)(r - NTOT) * DD + ks * 16 + h * 8];
            float4 q0 = p[0], q1 = p[1];
            v[0]=q0.x; v[1]=q0.y; v[2]=q0.z; v[3]=q0.w;
            v[4]=q1.x; v[5]=q1.y; v[6]=q1.z; v[7]=q1.w;
        } else {
#pragma unroll
            for (int j = 0; j < 8; ++j) v[j] = 0.f;
        }
        ushort8 H;
#pragma unroll
        for (int m = 0; m < 8; ++m) H[m] = f2bf_rne(v[m]);
        *(ushort8*)((char*)X2 + (size_t)b * 8192 + ks * 1024 + lane * 16) = H;
    }
}

// ---------------- epilogue for one 32x32 tile ----------------
__device__ __forceinline__ void epi_tile(
    const float16& acc, int cb, int lc, float rn, float drm, bool checkDiag,
    int half, int ln, int growbase, const int* rlab, float* sS, float* sN)
{
    const int ccol = cb * 32 + ln;
#pragma unroll
    for (int reg = 0; reg < 16; ++reg) {
        int ro = (reg & 3) + 8 * (reg >> 2) + 4 * half;
        float a  = acc[reg];
        float mf = (lc == rlab[reg]) ? 1.f : 0.f;
        float wgt = fmaf(mf, drm, rn);
        if (checkDiag) {                 // wave-uniform
            bool d = (ccol == growbase + ro);
            wgt = d ? 0.f : wgt;
            mf  = d ? 0.f : mf;
        }
        float e = exp2f(fmaf(a, K2E, -K2E));
        sS[reg] = fmaf(e, wgt, sS[reg]);
        sN[reg] = fmaf(mf, a, sN[reg]);  // un-scaled dot; *INV_T at finalize
    }
}

// ---------------- dual-stream pair of 32x32 tiles (R2's inner shape) ----------------
__device__ __forceinline__ void pair_tiles(
    const char* Xb, int cb0, int cb1,
    int lc0, float rn0, float drm0, bool dg0,
    int lc1, float rn1, float drm1, bool dg1,
    int lane, int half, int ln, int growbase,
    const short8* Ah, const int* rlab, float* sS, float* sN)
{
    const size_t b0 = (size_t)cb0 * 8192 + (size_t)lane * 16;
    const size_t b1 = (size_t)cb1 * 8192 + (size_t)lane * 16;
    float16 a0, a1;
#pragma unroll
    for (int reg = 0; reg < 16; ++reg) { a0[reg] = 0.f; a1[reg] = 0.f; }
#pragma unroll
    for (int ks = 0; ks < 8; ++ks) {
        short8 B0 = *(const short8*)(Xb + b0 + (size_t)ks * 1024);
        short8 B1 = *(const short8*)(Xb + b1 + (size_t)ks * 1024);
        a0 = __builtin_amdgcn_mfma_f32_32x32x16_bf16(Ah[ks], B0, a0, 0, 0, 0);
        a1 = __builtin_amdgcn_mfma_f32_32x32x16_bf16(Ah[ks], B1, a1, 0, 0, 0);
    }
    epi_tile(a0, cb0, lc0, rn0, drm0, dg0, half, ln, growbase, rlab, sS, sN);
    epi_tile(a1, cb1, lc1, rn1, drm1, dg1, half, ln, growbase, rlab, sS, sN);
}

// ---------------- branch-2 GEMM: grid (8, 132), block 256 ----------------
__global__ __launch_bounds__(256) void gemm2_k(
    const unsigned short* __restrict__ X2, const int* __restrict__ labels,
    const int* __restrict__ cntAll, float* __restrict__ pS, float* __restrict__ pN) {
    const int tid = threadIdx.x;
    const int lane = tid & 63, w = tid >> 6;
    const int half = lane >> 5, ln = lane & 31;
    const int rt = blockIdx.x, cg = blockIdx.y;
    const int rb = rt * 4 + w;
    const int growbase = rt * 128 + w * 32;
    const char* Xb = (const char*)X2;

    short8 Ah[8];
    {
        size_t abase = (size_t)rb * 8192 + (size_t)lane * 16;
#pragma unroll
        for (int ks = 0; ks < 8; ++ks)
            Ah[ks] = *(const short8*)(Xb + abase + (size_t)ks * 1024);
    }
    int rlab[16];
#pragma unroll
    for (int reg = 0; reg < 16; ++reg) {
        int ro = (reg & 3) + 8 * (reg >> 2) + 4 * half;
        rlab[reg] = labels[growbase + ro];
    }
    float sS[16], sN[16];
#pragma unroll
    for (int reg = 0; reg < 16; ++reg) { sS[reg] = 0.f; sN[reg] = 0.f; }

#pragma unroll
    for (int p = 0; p < 4; ++p) {
        const int cb0 = cg * 8 + 2 * p, cb1 = cb0 + 1;
        int lc0 = labels[cb0 * 32 + ln];
        int lc1 = labels[cb1 * 32 + ln];
        float c0 = (float)cntAll[lc0], c1 = (float)cntAll[lc1];
        float rn0 = __builtin_amdgcn_rcpf(c0);
        float drm0 = __builtin_amdgcn_rcpf(c0 - ALPHA) - rn0;
        float rn1 = __builtin_amdgcn_rcpf(c1);
        float drm1 = __builtin_amdgcn_rcpf(c1 - ALPHA) - rn1;
        pair_tiles(Xb, cb0, cb1, lc0, rn0, drm0, cb0 == rb,
                   lc1, rn1, drm1, cb1 == rb,
                   lane, half, ln, growbase, Ah, rlab, sS, sN);
    }
#pragma unroll
    for (int reg = 0; reg < 16; ++reg) {
        float a = sS[reg], c = sN[reg];
#pragma unroll
        for (int off = 1; off < 32; off <<= 1) {
            a += __shfl_xor(a, off, 64);
            c += __shfl_xor(c, off, 64);
        }
        if (ln == 0) {
            int ro = (reg & 3) + 8 * (reg >> 2) + 4 * half;
            int grow = growbase + ro;
            pS[(size_t)cg * BB + grow] = a;
            pN[(size_t)cg * BB + grow] = c;
        }
    }
}

// ---------------- branch-1 GEMM + sup-sums: grid (8, 10) ----------------
// cg 0..7: batch cols (4 cb). cg 8: center cbs. cg 9: sup-logits sums.
__global__ __launch_bounds__(256) void gemm1_k(
    const unsigned short* __restrict__ X2, const int* __restrict__ labels,
    const int* __restrict__ cntBatch, const int* __restrict__ cntAll,
    const float* __restrict__ sup,
    float* __restrict__ pS, float* __restrict__ pN,
    float* __restrict__ supS, float* __restrict__ supLi) {
    const int tid = threadIdx.x;
    const int lane = tid & 63, w = tid >> 6;
    const int half = lane >> 5, ln = lane & 31;
    const int rt = blockIdx.x, cg = blockIdx.y;
    const char* Xb = (const char*)X2;

    if (cg == 9) {  // sup-logits exp-sums, coalesced (lane = class), wave = 32 rows
        const int g = rt * 4 + w;
        const int c0 = lane, c1 = lane + 64;
        float n0 = (float)cntAll[c0];
        float rA0 = __builtin_amdgcn_rcpf(n0);
        float rAm0 = __builtin_amdgcn_rcpf(fmaxf(n0 - 1.f, 1.f));
        float rA1 = 0.f, rAm1 = 0.f;
        if (lane < 36) {
            float n1 = (float)cntAll[c1];
            rA1 = __builtin_amdgcn_rcpf(n1);
            rAm1 = __builtin_amdgcn_rcpf(fmaxf(n1 - 1.f, 1.f));
        }
        for (int rr = 0; rr < 32; ++rr) {
            int row = g * 32 + rr;
            int li = labels[row];
            const float* srow = &sup[(size_t)row * CC];
            float v0 = srow[c0];
            float s = __expf(v0 - INV_T) * ((c0 == li) ? rAm0 : rA0);
            float liv = (c0 == li) ? v0 : 0.f;
            if (lane < 36) {
                float v1 = srow[c1];
                s += __expf(v1 - INV_T) * ((c1 == li) ? rAm1 : rA1);
                liv += (c1 == li) ? v1 : 0.f;
            }
#pragma unroll
            for (int off = 1; off < 64; off <<= 1) {
                s += __shfl_xor(s, off, 64);
                liv += __shfl_xor(liv, off, 64);
            }
            if (lane == 0) { supS[row] = s; supLi[row] = liv; }
        }
        return;
    }

    const int rb = rt * 4 + w;
    const int growbase = rt * 128 + w * 32;
    short8 Ah[8];
    {
        size_t abase = (size_t)rb * 8192 + (size_t)lane * 16;
#pragma unroll
        for (int ks = 0; ks < 8; ++ks)
            Ah[ks] = *(const short8*)(Xb + abase + (size_t)ks * 1024);
    }
    int rlab[16];
#pragma unroll
    for (int reg = 0; reg < 16; ++reg) {
        int ro = (reg & 3) + 8 * (reg >> 2) + 4 * half;
        rlab[reg] = labels[growbase + ro];
    }
    float sS[16], sN[16];
#pragma unroll
    for (int reg = 0; reg < 16; ++reg) { sS[reg] = 0.f; sN[reg] = 0.f; }

    const bool isBatch = (cg < 8);
#pragma unroll
    for (int p = 0; p < 2; ++p) {
        int cb0, cb1, lc0, lc1;
        if (isBatch) {
            cb0 = cg * 4 + 2 * p; cb1 = cb0 + 1;
            lc0 = labels[cb0 * 32 + ln];
            lc1 = labels[cb1 * 32 + ln];
        } else {
            cb0 = CB_CENT + 2 * p; cb1 = cb0 + 1;
            int q0 = cb0 * 32 + ln - NTOT, q1 = cb1 * 32 + ln - NTOT;
            lc0 = (q0 < CC) ? q0 : -1;
            lc1 = (q1 < CC) ? q1 : -1;
        }
        float e0 = (float)((lc0 >= 0 ? cntBatch[lc0] : 0) + 1);
        float e1 = (float)((lc1 >= 0 ? cntBatch[lc1] : 0) + 1);
        float rn0 = (lc0 >= 0) ? __builtin_amdgcn_rcpf(e0) : 0.f;
        float rn1 = (lc1 >= 0) ? __builtin_amdgcn_rcpf(e1) : 0.f;
        float drm0 = (lc0 >= 0) ? (__builtin_amdgcn_rcpf(fmaxf(e0 - 1.f, 1.f)) - rn0) : 0.f;
        float drm1 = (lc1 >= 0) ? (__builtin_amdgcn_rcpf(fmaxf(e1 - 1.f, 1.f)) - rn1) : 0.f;
        pair_tiles(Xb, cb0, cb1, lc0, rn0, drm0, isBatch && (cb0 == rb),
                   lc1, rn1, drm1, isBatch && (cb1 == rb),
                   lane, half, ln, growbase, Ah, rlab, sS, sN);
    }
#pragma unroll
    for (int reg = 0; reg < 16; ++reg) {
        float a = sS[reg], c = sN[reg];
#pragma unroll
        for (int off = 1; off < 32; off <<= 1) {
            a += __shfl_xor(a, off, 64);
            c += __shfl_xor(c, off, 64);
        }
        if (ln == 0) {
            int ro = (reg & 3) + 8 * (reg >> 2) + 4 * half;
            int grow = growbase + ro;
            pS[(size_t)cg * BB + grow] = a;
            pN[(size_t)cg * BB + grow] = c;
        }
    }
}

// ---------------- finalize: 8 blocks x 128 threads, coalesced slice sums ----------------
__global__ __launch_bounds__(128) void finalize_k(
    const int* __restrict__ labels,
    const int* __restrict__ cntAll, const int* __restrict__ cntBatch,
    const float* __restrict__ p2S, const float* __restrict__ p2N,
    const float* __restrict__ p1S, const float* __restrict__ p1N,
    const float* __restrict__ supS, const float* __restrict__ supLi,
    float* __restrict__ out) {
    const int t = threadIdx.x;
    const int row = blockIdx.x * 128 + t;
    const int li = labels[row];
    float S2 = supS[row], N2 = 0.f;
    for (int c = 0; c < NCG2; ++c) {
        S2 += p2S[(size_t)c * BB + row];
        N2 += p2N[(size_t)c * BB + row];
    }
    float S1 = 0.f, N1v = 0.f;
#pragma unroll
    for (int c = 0; c < 9; ++c) {
        S1 += p1S[(size_t)c * BB + row];
        N1v += p1N[(size_t)c * BB + row];
    }
    N2 *= INV_T; N1v *= INV_T;
    float sli = supLi[row];
    float cA = (float)cntAll[li];
    float msum2 = fmaf(ALPHA, cA - 1.f, 1.f);
    float loss2 = -(fmaf(ALPHA, N2, sli) / msum2 - INV_T - logf(S2 + EPSV));
    float loss1 = -(N1v / (float)cntBatch[li] - INV_T - logf(S1 + EPSV));
    float s = (loss1 + loss2) * (1.0f / (float)BB);
    __shared__ float buf[2];
#pragma unroll
    for (int off = 1; off < 64; off <<= 1) s += __shfl_xor(s, off, 64);
    if ((t & 63) == 0) buf[t >> 6] = s;
    __syncthreads();
    if (t == 0) atomicAdd(out, buf[0] + buf[1]);
}

extern "C" void kernel_launch(void* const* d_in, const int* in_sizes, int n_in,
                              void* d_out, int out_size, void* d_ws, size_t ws_size,
                              hipStream_t stream) {
    const float* feats   = (const float*)d_in[0];
    const float* sup     = (const float*)d_in[1];
    const float* centers = (const float*)d_in[2];
    const int*   labels  = (const int*)d_in[3];
    float* out = (float*)d_out;
    char*  wsb = (char*)d_ws;

    const size_t X2_BYTES = (size_t)NCB * 8192;         // 8,683,520
    unsigned short* X2 = (unsigned short*)wsb;
    char* base2 = wsb + X2_BYTES;
    int* cntAll   = (int*)base2;                        // 128 ints
    int* cntBatch = cntAll + 128;                       // 128 ints
    float* p2S = (float*)(base2 + 1024);                // 132*1024
    float* p2N = p2S + (size_t)NCG2 * BB;
    float* p1S = p2N + (size_t)NCG2 * BB;               // 9*1024
    float* p1N = p1S + (size_t)9 * BB;
    float* supS  = p1N + (size_t)9 * BB;                // 1024
    float* supLi = supS + BB;                           // 1024

    hipMemsetAsync(base2, 0, 1024, stream);             // counters
    hipMemsetAsync(out, 0, sizeof(float), stream);      // loss accumulator
    prep_k<<<NCB + NHIST, 256, 0, stream>>>(feats, centers, labels, X2, cntAll, cntBatch);
    gemm2_k<<<dim3(8, NCG2), 256, 0, stream>>>(X2, labels, cntAll, p2S, p2N);
    gemm1_k<<<dim3(8, 10), 256, 0, stream>>>(X2, labels, cntBatch, cntAll, sup,
                                             p1S, p1N, supS, supLi);
    finalize_k<<<8, 128, 0, stream>>>(labels, cntAll, cntBatch, p2S, p2N, p1S, p1N,
                                      supS, supLi, out);
}

// Round 9
// 181.160 us; speedup vs baseline: 1.0201x; 1.0201x over previous
//
#include <hip/hip_runtime.h>
#include <math.h>

#define KQ   32768
#define CC   100
#define BB   1024
#define DD   128
#define NTOT (BB + KQ)        // 33792
#define CB_CENT 1056
#define NCB  1060             // 32-row blocks in X2
#define NHIST 33              // histogram blocks
#define NCG2 132              // branch-2 col groups (8 cb each)

#define INV_T  14.285714285714286f
#define K2E    20.609929f     // INV_T * log2(e)
#define ALPHA  0.05f
#define EPSV   1e-12f

typedef __attribute__((ext_vector_type(8)))  short          short8;
typedef __attribute__((ext_vector_type(8)))  unsigned short ushort8;
typedef __attribute__((ext_vector_type(16))) float          float16;

__device__ __forceinline__ unsigned short f2bf_rne(float f) {
    unsigned int u = __float_as_uint(f);
    return (unsigned short)((u + 0x7FFFu + ((u >> 16) & 1u)) >> 16);
}

// X2 layout per 32-row block cb (8192 B): [ks 0..7][lane 0..63][16 B]
// element (row r, k): cb=r>>5, ks=k>>4, lane=(r&31)+32*((k>>3)&1), j=k&7
// == 32x32x16 MFMA A/B operand layout (verified R2-R8).

// ---------------- prep: coalesced read -> padded-LDS transpose -> coalesced write ----------------
__global__ __launch_bounds__(256) void prep_k(const float* __restrict__ feats,
                                              const float* __restrict__ centers,
                                              const int* __restrict__ labels,
                                              unsigned short* __restrict__ X2,
                                              int* __restrict__ cntAll,
                                              int* __restrict__ cntBatch) {
    const int b = blockIdx.x, t = threadIdx.x;
    if (b >= NCB) {  // histogram: LDS-local then one global atomic per bin
        __shared__ int hA[CC], hB[CC];
        if (t < CC) { hA[t] = 0; hB[t] = 0; }
        __syncthreads();
        const int base = (b - NCB) * 1024;
#pragma unroll
        for (int q = 0; q < 4; ++q) {
            int idx = base + q * 256 + t;
            int l = labels[idx];
            atomicAdd(&hA[l], 1);
            if (idx < BB) atomicAdd(&hB[l], 1);
        }
        __syncthreads();
        if (t < CC) {
            if (hA[t]) atomicAdd(&cntAll[t], hA[t]);
            if (hB[t]) atomicAdd(&cntBatch[t], hB[t]);
        }
        return;
    }
    // stride-66 slot padding: b128 LDS writes land 2 lanes/bank-quad (free),
    // copy-phase reads are stride-1 (conflict-free).
    __shared__ unsigned short sm[8 * 66 * 8];   // 8448 B
    const int rl = t >> 3, c8 = t & 7;
    const int r = b * 32 + rl;
    const float* src;
    if (r < NTOT)            src = &feats[(size_t)r * DD];
    else if (r < NTOT + CC)  src = &centers[(size_t)(r - NTOT) * DD];
    else                     src = nullptr;
#pragma unroll
    for (int s = 0; s < 2; ++s) {
        const int c8p = c8 + 8 * s;             // 0..15: which 8-float chunk of the row
        float v[8];
        if (src) {
            const float4* p = (const float4*)(src + c8p * 8);
            float4 q0 = p[0], q1 = p[1];
            v[0]=q0.x; v[1]=q0.y; v[2]=q0.z; v[3]=q0.w;
            v[4]=q1.x; v[5]=q1.y; v[6]=q1.z; v[7]=q1.w;
        } else {
#pragma unroll
            for (int j = 0; j < 8; ++j) v[j] = 0.f;
        }
        ushort8 H;
#pragma unroll
        for (int m = 0; m < 8; ++m) H[m] = f2bf_rne(v[m]);
        const int ks = c8p >> 1, lh = c8p & 1;
        const int slot = ks * 66 + rl + 32 * lh;
        *(ushort8*)&sm[slot * 8] = H;
    }
    __syncthreads();
    ushort8* dst = (ushort8*)((char*)X2 + (size_t)b * 8192);
#pragma unroll
    for (int j = 0; j < 2; ++j) {
        const int idx = j * 256 + t;            // 0..511
        const int ks = idx >> 6, ln = idx & 63;
        dst[idx] = *(const ushort8*)&sm[(ks * 66 + ln) * 8];
    }
}

// ---------------- epilogue for one 32x32 tile ----------------
__device__ __forceinline__ void epi_tile(
    const float16& acc, int cb, int lc, float rn, float drm, bool checkDiag,
    int half, int ln, int growbase, const int* rlab, float* sS, float* sN)
{
    const int ccol = cb * 32 + ln;
#pragma unroll
    for (int reg = 0; reg < 16; ++reg) {
        int ro = (reg & 3) + 8 * (reg >> 2) + 4 * half;
        float a  = acc[reg];
        float mf = (lc == rlab[reg]) ? 1.f : 0.f;
        float wgt = fmaf(mf, drm, rn);
        if (checkDiag) {                 // wave-uniform
            bool d = (ccol == growbase + ro);
            wgt = d ? 0.f : wgt;
            mf  = d ? 0.f : mf;
        }
        float e = exp2f(fmaf(a, K2E, -K2E));
        sS[reg] = fmaf(e, wgt, sS[reg]);
        sN[reg] = fmaf(mf, a, sN[reg]);  // un-scaled dot; *INV_T at finalize
    }
}

// ---------------- dual-stream pair of 32x32 tiles (R8's proven inner shape) ----------------
__device__ __forceinline__ void pair_tiles(
    const char* Xb, int cb0, int cb1,
    int lc0, float rn0, float drm0, bool dg0,
    int lc1, float rn1, float drm1, bool dg1,
    int lane, int half, int ln, int growbase,
    const short8* Ah, const int* rlab, float* sS, float* sN)
{
    const size_t b0 = (size_t)cb0 * 8192 + (size_t)lane * 16;
    const size_t b1 = (size_t)cb1 * 8192 + (size_t)lane * 16;
    float16 a0, a1;
#pragma unroll
    for (int reg = 0; reg < 16; ++reg) { a0[reg] = 0.f; a1[reg] = 0.f; }
#pragma unroll
    for (int ks = 0; ks < 8; ++ks) {
        short8 B0 = *(const short8*)(Xb + b0 + (size_t)ks * 1024);
        short8 B1 = *(const short8*)(Xb + b1 + (size_t)ks * 1024);
        a0 = __builtin_amdgcn_mfma_f32_32x32x16_bf16(Ah[ks], B0, a0, 0, 0, 0);
        a1 = __builtin_amdgcn_mfma_f32_32x32x16_bf16(Ah[ks], B1, a1, 0, 0, 0);
    }
    epi_tile(a0, cb0, lc0, rn0, drm0, dg0, half, ln, growbase, rlab, sS, sN);
    epi_tile(a1, cb1, lc1, rn1, drm1, dg1, half, ln, growbase, rlab, sS, sN);
}

// ---------------- branch-2 GEMM: 1-D grid 1088, XCD-swizzled ----------------
// b: xcd = b&7 (maps to XCD via id%8 dispatch), l = b>>3: rt = l&7 (fastest ->
// the 8 rt-blocks sharing one cg run concurrently on their XCD), ci = l>>3.
// cg = xcd + 8*ci; per-XCD B-footprint = 17 cgs x 64 KB ~ 1.1 MB << 4 MB L2.
__global__ __launch_bounds__(256) void gemm2_k(
    const unsigned short* __restrict__ X2, const int* __restrict__ labels,
    const int* __restrict__ cntAll, float* __restrict__ pS, float* __restrict__ pN) {
    const int b = blockIdx.x;
    const int xcd = b & 7, l = b >> 3;
    const int rt = l & 7, ci = l >> 3;
    const int cg = xcd + 8 * ci;
    if (cg >= NCG2) return;

    const int tid = threadIdx.x;
    const int lane = tid & 63, w = tid >> 6;
    const int half = lane >> 5, ln = lane & 31;
    const int rb = rt * 4 + w;
    const int growbase = rt * 128 + w * 32;
    const char* Xb = (const char*)X2;

    short8 Ah[8];
    {
        size_t abase = (size_t)rb * 8192 + (size_t)lane * 16;
#pragma unroll
        for (int ks = 0; ks < 8; ++ks)
            Ah[ks] = *(const short8*)(Xb + abase + (size_t)ks * 1024);
    }
    int rlab[16];
#pragma unroll
    for (int reg = 0; reg < 16; ++reg) {
        int ro = (reg & 3) + 8 * (reg >> 2) + 4 * half;
        rlab[reg] = labels[growbase + ro];
    }
    float sS[16], sN[16];
#pragma unroll
    for (int reg = 0; reg < 16; ++reg) { sS[reg] = 0.f; sN[reg] = 0.f; }

#pragma unroll
    for (int p = 0; p < 4; ++p) {
        const int cb0 = cg * 8 + 2 * p, cb1 = cb0 + 1;
        int lc0 = labels[cb0 * 32 + ln];
        int lc1 = labels[cb1 * 32 + ln];
        float c0 = (float)cntAll[lc0], c1 = (float)cntAll[lc1];
        float rn0 = __builtin_amdgcn_rcpf(c0);
        float drm0 = __builtin_amdgcn_rcpf(c0 - ALPHA) - rn0;
        float rn1 = __builtin_amdgcn_rcpf(c1);
        float drm1 = __builtin_amdgcn_rcpf(c1 - ALPHA) - rn1;
        pair_tiles(Xb, cb0, cb1, lc0, rn0, drm0, cb0 == rb,
                   lc1, rn1, drm1, cb1 == rb,
                   lane, half, ln, growbase, Ah, rlab, sS, sN);
    }
#pragma unroll
    for (int reg = 0; reg < 16; ++reg) {
        float a = sS[reg], c = sN[reg];
#pragma unroll
        for (int off = 1; off < 32; off <<= 1) {
            a += __shfl_xor(a, off, 64);
            c += __shfl_xor(c, off, 64);
        }
        if (ln == 0) {
            int ro = (reg & 3) + 8 * (reg >> 2) + 4 * half;
            int grow = growbase + ro;
            pS[(size_t)cg * BB + grow] = a;
            pN[(size_t)cg * BB + grow] = c;
        }
    }
}

// ---------------- branch-1 GEMM + sup-sums: grid (8, 10) ----------------
// cg 0..7: batch cols (4 cb). cg 8: center cbs. cg 9: sup-logits sums.
__global__ __launch_bounds__(256) void gemm1_k(
    const unsigned short* __restrict__ X2, const int* __restrict__ labels,
    const int* __restrict__ cntBatch, const int* __restrict__ cntAll,
    const float* __restrict__ sup,
    float* __restrict__ pS, float* __restrict__ pN,
    float* __restrict__ supS, float* __restrict__ supLi) {
    const int tid = threadIdx.x;
    const int lane = tid & 63, w = tid >> 6;
    const int half = lane >> 5, ln = lane & 31;
    const int rt = blockIdx.x, cg = blockIdx.y;
    const char* Xb = (const char*)X2;

    if (cg == 9) {  // sup-logits exp-sums, coalesced (lane = class), wave = 32 rows
        const int g = rt * 4 + w;
        const int c0 = lane, c1 = lane + 64;
        float n0 = (float)cntAll[c0];
        float rA0 = __builtin_amdgcn_rcpf(n0);
        float rAm0 = __builtin_amdgcn_rcpf(fmaxf(n0 - 1.f, 1.f));
        float rA1 = 0.f, rAm1 = 0.f;
        if (lane < 36) {
            float n1 = (float)cntAll[c1];
            rA1 = __builtin_amdgcn_rcpf(n1);
            rAm1 = __builtin_amdgcn_rcpf(fmaxf(n1 - 1.f, 1.f));
        }
        for (int rr = 0; rr < 32; ++rr) {
            int row = g * 32 + rr;
            int li = labels[row];
            const float* srow = &sup[(size_t)row * CC];
            float v0 = srow[c0];
            float s = __expf(v0 - INV_T) * ((c0 == li) ? rAm0 : rA0);
            float liv = (c0 == li) ? v0 : 0.f;
            if (lane < 36) {
                float v1 = srow[c1];
                s += __expf(v1 - INV_T) * ((c1 == li) ? rAm1 : rA1);
                liv += (c1 == li) ? v1 : 0.f;
            }
#pragma unroll
            for (int off = 1; off < 64; off <<= 1) {
                s += __shfl_xor(s, off, 64);
                liv += __shfl_xor(liv, off, 64);
            }
            if (lane == 0) { supS[row] = s; supLi[row] = liv; }
        }
        return;
    }

    const int rb = rt * 4 + w;
    const int growbase = rt * 128 + w * 32;
    short8 Ah[8];
    {
        size_t abase = (size_t)rb * 8192 + (size_t)lane * 16;
#pragma unroll
        for (int ks = 0; ks < 8; ++ks)
            Ah[ks] = *(const short8*)(Xb + abase + (size_t)ks * 1024);
    }
    int rlab[16];
#pragma unroll
    for (int reg = 0; reg < 16; ++reg) {
        int ro = (reg & 3) + 8 * (reg >> 2) + 4 * half;
        rlab[reg] = labels[growbase + ro];
    }
    float sS[16], sN[16];
#pragma unroll
    for (int reg = 0; reg < 16; ++reg) { sS[reg] = 0.f; sN[reg] = 0.f; }

    const bool isBatch = (cg < 8);
#pragma unroll
    for (int p = 0; p < 2; ++p) {
        int cb0, cb1, lc0, lc1;
        if (isBatch) {
            cb0 = cg * 4 + 2 * p; cb1 = cb0 + 1;
            lc0 = labels[cb0 * 32 + ln];
            lc1 = labels[cb1 * 32 + ln];
        } else {
            cb0 = CB_CENT + 2 * p; cb1 = cb0 + 1;
            int q0 = cb0 * 32 + ln - NTOT, q1 = cb1 * 32 + ln - NTOT;
            lc0 = (q0 < CC) ? q0 : -1;
            lc1 = (q1 < CC) ? q1 : -1;
        }
        float e0 = (float)((lc0 >= 0 ? cntBatch[lc0] : 0) + 1);
        float e1 = (float)((lc1 >= 0 ? cntBatch[lc1] : 0) + 1);
        float rn0 = (lc0 >= 0) ? __builtin_amdgcn_rcpf(e0) : 0.f;
        float rn1 = (lc1 >= 0) ? __builtin_amdgcn_rcpf(e1) : 0.f;
        float drm0 = (lc0 >= 0) ? (__builtin_amdgcn_rcpf(fmaxf(e0 - 1.f, 1.f)) - rn0) : 0.f;
        float drm1 = (lc1 >= 0) ? (__builtin_amdgcn_rcpf(fmaxf(e1 - 1.f, 1.f)) - rn1) : 0.f;
        pair_tiles(Xb, cb0, cb1, lc0, rn0, drm0, isBatch && (cb0 == rb),
                   lc1, rn1, drm1, isBatch && (cb1 == rb),
                   lane, half, ln, growbase, Ah, rlab, sS, sN);
    }
#pragma unroll
    for (int reg = 0; reg < 16; ++reg) {
        float a = sS[reg], c = sN[reg];
#pragma unroll
        for (int off = 1; off < 32; off <<= 1) {
            a += __shfl_xor(a, off, 64);
            c += __shfl_xor(c, off, 64);
        }
        if (ln == 0) {
            int ro = (reg & 3) + 8 * (reg >> 2) + 4 * half;
            int grow = growbase + ro;
            pS[(size_t)cg * BB + grow] = a;
            pN[(size_t)cg * BB + grow] = c;
        }
    }
}

// ---------------- finalize: 8 blocks x 128 threads, coalesced slice sums ----------------
__global__ __launch_bounds__(128) void finalize_k(
    const int* __restrict__ labels,
    const int* __restrict__ cntAll, const int* __restrict__ cntBatch,
    const float* __restrict__ p2S, const float* __restrict__ p2N,
    const float* __restrict__ p1S, const float* __restrict__ p1N,
    const float* __restrict__ supS, const float* __restrict__ supLi,
    float* __restrict__ out) {
    const int t = threadIdx.x;
    const int row = blockIdx.x * 128 + t;
    const int li = labels[row];
    float S2 = supS[row], N2 = 0.f;
    for (int c = 0; c < NCG2; ++c) {
        S2 += p2S[(size_t)c * BB + row];
        N2 += p2N[(size_t)c * BB + row];
    }
    float S1 = 0.f, N1v = 0.f;
#pragma unroll
    for (int c = 0; c < 9; ++c) {
        S1 += p1S[(size_t)c * BB + row];
        N1v += p1N[(size_t)c * BB + row];
    }
    N2 *= INV_T; N1v *= INV_T;
    float sli = supLi[row];
    float cA = (float)cntAll[li];
    float msum2 = fmaf(ALPHA, cA - 1.f, 1.f);
    float loss2 = -(fmaf(ALPHA, N2, sli) / msum2 - INV_T - logf(S2 + EPSV));
    float loss1 = -(N1v / (float)cntBatch[li] - INV_T - logf(S1 + EPSV));
    float s = (loss1 + loss2) * (1.0f / (float)BB);
    __shared__ float buf[2];
#pragma unroll
    for (int off = 1; off < 64; off <<= 1) s += __shfl_xor(s, off, 64);
    if ((t & 63) == 0) buf[t >> 6] = s;
    __syncthreads();
    if (t == 0) atomicAdd(out, buf[0] + buf[1]);
}

extern "C" void kernel_launch(void* const* d_in, const int* in_sizes, int n_in,
                              void* d_out, int out_size, void* d_ws, size_t ws_size,
                              hipStream_t stream) {
    const float* feats   = (const float*)d_in[0];
    const float* sup     = (const float*)d_in[1];
    const float* centers = (const float*)d_in[2];
    const int*   labels  = (const int*)d_in[3];
    float* out = (float*)d_out;
    char*  wsb = (char*)d_ws;

    const size_t X2_BYTES = (size_t)NCB * 8192;         // 8,683,520
    unsigned short* X2 = (unsigned short*)wsb;
    char* base2 = wsb + X2_BYTES;
    int* cntAll   = (int*)base2;                        // 128 ints
    int* cntBatch = cntAll + 128;                       // 128 ints
    float* p2S = (float*)(base2 + 1024);                // 132*1024
    float* p2N = p2S + (size_t)NCG2 * BB;
    float* p1S = p2N + (size_t)NCG2 * BB;               // 9*1024
    float* p1N = p1S + (size_t)9 * BB;
    float* supS  = p1N + (size_t)9 * BB;                // 1024
    float* supLi = supS + BB;                           // 1024

    hipMemsetAsync(base2, 0, 1024, stream);             // counters
    hipMemsetAsync(out, 0, sizeof(float), stream);      // loss accumulator
    prep_k<<<NCB + NHIST, 256, 0, stream>>>(feats, centers, labels, X2, cntAll, cntBatch);
    gemm2_k<<<8 * 8 * 17, 256, 0, stream>>>(X2, labels, cntAll, p2S, p2N);
    gemm1_k<<<dim3(8, 10), 256, 0, stream>>>(X2, labels, cntBatch, cntAll, sup,
                                             p1S, p1N, supS, supLi);
    finalize_k<<<8, 128, 0, stream>>>(labels, cntAll, cntBatch, p2S, p2N, p1S, p1N,
                                      supS, supLi, out);
}

// Round 10
// 160.982 us; speedup vs baseline: 1.1480x; 1.1253x over previous
//
#include <hip/hip_runtime.h>
#include <math.h>

#define KQ   32768
#define CC   100
#define BB   1024
#define DD   128
#define NTOT (BB + KQ)        // 33792
#define CB_CENT 1056
#define NCB  1060             // 32-row blocks in X2
#define NHIST 33              // histogram blocks
#define NCG2 132              // branch-2 col groups (8 cb each)
#define CG_SUP 141            // sup-logits group (after 9 branch-1 groups)

#define INV_T  14.285714285714286f
#define K2E    20.609929f     // INV_T * log2(e)
#define ALPHA  0.05f
#define EPSV   1e-12f

typedef __attribute__((ext_vector_type(8)))  short          short8;
typedef __attribute__((ext_vector_type(8)))  unsigned short ushort8;
typedef __attribute__((ext_vector_type(16))) float          float16;

__device__ __forceinline__ unsigned short f2bf_rne(float f) {
    unsigned int u = __float_as_uint(f);
    return (unsigned short)((u + 0x7FFFu + ((u >> 16) & 1u)) >> 16);
}

// X2 layout per 32-row block cb (8192 B): [ks 0..7][lane 0..63][16 B]
// element (row r, k): cb=r>>5, ks=k>>4, lane=(r&31)+32*((k>>3)&1), j=k&7
// == 32x32x16 MFMA A/B operand layout (verified R2-R9).

// ---------------- prep: coalesced read -> padded-LDS transpose -> coalesced write ----------------
__global__ __launch_bounds__(256) void prep_k(const float* __restrict__ feats,
                                              const float* __restrict__ centers,
                                              const int* __restrict__ labels,
                                              unsigned short* __restrict__ X2,
                                              int* __restrict__ cntAll,
                                              int* __restrict__ cntBatch) {
    const int b = blockIdx.x, t = threadIdx.x;
    if (b >= NCB) {  // histogram: LDS-local then one global atomic per bin
        __shared__ int hA[CC], hB[CC];
        if (t < CC) { hA[t] = 0; hB[t] = 0; }
        __syncthreads();
        const int base = (b - NCB) * 1024;
#pragma unroll
        for (int q = 0; q < 4; ++q) {
            int idx = base + q * 256 + t;
            int l = labels[idx];
            atomicAdd(&hA[l], 1);
            if (idx < BB) atomicAdd(&hB[l], 1);
        }
        __syncthreads();
        if (t < CC) {
            if (hA[t]) atomicAdd(&cntAll[t], hA[t]);
            if (hB[t]) atomicAdd(&cntBatch[t], hB[t]);
        }
        return;
    }
    __shared__ unsigned short sm[8 * 66 * 8];   // stride-66 slots: conflict-free both phases
    const int rl = t >> 3, c8 = t & 7;
    const int r = b * 32 + rl;
    const float* src;
    if (r < NTOT)            src = &feats[(size_t)r * DD];
    else if (r < NTOT + CC)  src = &centers[(size_t)(r - NTOT) * DD];
    else                     src = nullptr;
#pragma unroll
    for (int s = 0; s < 2; ++s) {
        const int c8p = c8 + 8 * s;
        float v[8];
        if (src) {
            const float4* p = (const float4*)(src + c8p * 8);
            float4 q0 = p[0], q1 = p[1];
            v[0]=q0.x; v[1]=q0.y; v[2]=q0.z; v[3]=q0.w;
            v[4]=q1.x; v[5]=q1.y; v[6]=q1.z; v[7]=q1.w;
        } else {
#pragma unroll
            for (int j = 0; j < 8; ++j) v[j] = 0.f;
        }
        ushort8 H;
#pragma unroll
        for (int m = 0; m < 8; ++m) H[m] = f2bf_rne(v[m]);
        const int ks = c8p >> 1, lh = c8p & 1;
        *(ushort8*)&sm[(ks * 66 + rl + 32 * lh) * 8] = H;
    }
    __syncthreads();
    ushort8* dst = (ushort8*)((char*)X2 + (size_t)b * 8192);
#pragma unroll
    for (int j = 0; j < 2; ++j) {
        const int idx = j * 256 + t;
        const int ks = idx >> 6, ln = idx & 63;
        dst[idx] = *(const ushort8*)&sm[(ks * 66 + ln) * 8];
    }
}

// ---------------- async stage one 8 KB B-block into LDS (m97 pattern) ----------------
__device__ __forceinline__ void stage_cb(const char* Xb, int cb, char* dstbase,
                                         int w, int lane) {
    const char* g = Xb + (size_t)cb * 8192 + (size_t)w * 2048 + (size_t)lane * 16;
    char* lp = dstbase + w * 2048;   // wave-uniform base; HW scatters lane*16
#pragma unroll
    for (int c = 0; c < 2; ++c)
        __builtin_amdgcn_global_load_lds(
            (const __attribute__((address_space(1))) unsigned int*)(g + c * 1024),
            (__attribute__((address_space(3))) unsigned int*)(lp + c * 1024),
            16, 0, 0);
}

// ---------------- compute one 32x32 tile from LDS ----------------
__device__ __forceinline__ void tile_lds(
    const char* buf, int cb, int lc, float rn, float drm, bool checkDiag,
    int lane, int half, int ln, int growbase,
    const short8* Ah, const int* rlab, float* sS, float* sN)
{
    const char* bp = buf + lane * 16;
    float16 acc;
#pragma unroll
    for (int reg = 0; reg < 16; ++reg) acc[reg] = 0.f;
#pragma unroll
    for (int ks = 0; ks < 8; ++ks) {
        short8 Bv = *(const short8*)(bp + ks * 1024);   // ds_read_b128, conflict-free
        acc = __builtin_amdgcn_mfma_f32_32x32x16_bf16(Ah[ks], Bv, acc, 0, 0, 0);
    }
    const int ccol = cb * 32 + ln;
#pragma unroll
    for (int reg = 0; reg < 16; ++reg) {
        int ro = (reg & 3) + 8 * (reg >> 2) + 4 * half;
        float a  = acc[reg];
        float mf = (lc == rlab[reg]) ? 1.f : 0.f;
        float wgt = fmaf(mf, drm, rn);
        if (checkDiag) {                 // wave-uniform
            bool d = (ccol == growbase + ro);
            wgt = d ? 0.f : wgt;
            mf  = d ? 0.f : mf;
        }
        float e = exp2f(fmaf(a, K2E, -K2E));
        sS[reg] = fmaf(e, wgt, sS[reg]);
        sN[reg] = fmaf(mf, a, sN[reg]);  // un-scaled dot; *INV_T at finalize
    }
}

// ---------------- fused GEMM (b2 + b1) + sup-sums, LDS double-buffered ----------------
// grid 1152 = 8 xcd * 8 rt * 18 ci; cg = xcd + 8*ci.
// cg<132: branch2 (8 cb). 132..140: branch1 (4 cb). 141: sup sums. >141: idle.
__global__ __launch_bounds__(256) void gemm_k(
    const unsigned short* __restrict__ X2, const int* __restrict__ labels,
    const int* __restrict__ cntAll, const int* __restrict__ cntBatch,
    const float* __restrict__ sup,
    float* __restrict__ p2S, float* __restrict__ p2N,
    float* __restrict__ p1S, float* __restrict__ p1N,
    float* __restrict__ supS, float* __restrict__ supLi) {
    const int b = blockIdx.x;
    const int xcd = b & 7, l = b >> 3;
    const int rt = l & 7, ci = l >> 3;
    const int cg = xcd + 8 * ci;
    if (cg > CG_SUP) return;

    const int tid = threadIdx.x;
    const int lane = tid & 63, w = tid >> 6;
    const int half = lane >> 5, ln = lane & 31;
    const char* Xb = (const char*)X2;

    if (cg == CG_SUP) {  // sup-logits exp-sums, coalesced (lane = class), wave = 32 rows
        const int g = rt * 4 + w;
        const int c0 = lane, c1 = lane + 64;
        float n0 = (float)cntAll[c0];
        float rA0 = __builtin_amdgcn_rcpf(n0);
        float rAm0 = __builtin_amdgcn_rcpf(fmaxf(n0 - 1.f, 1.f));
        float rA1 = 0.f, rAm1 = 0.f;
        if (lane < 36) {
            float n1 = (float)cntAll[c1];
            rA1 = __builtin_amdgcn_rcpf(n1);
            rAm1 = __builtin_amdgcn_rcpf(fmaxf(n1 - 1.f, 1.f));
        }
        for (int rr = 0; rr < 32; ++rr) {
            int row = g * 32 + rr;
            int li = labels[row];
            const float* srow = &sup[(size_t)row * CC];
            float v0 = srow[c0];
            float s = __expf(v0 - INV_T) * ((c0 == li) ? rAm0 : rA0);
            float liv = (c0 == li) ? v0 : 0.f;
            if (lane < 36) {
                float v1 = srow[c1];
                s += __expf(v1 - INV_T) * ((c1 == li) ? rAm1 : rA1);
                liv += (c1 == li) ? v1 : 0.f;
            }
#pragma unroll
            for (int off = 1; off < 64; off <<= 1) {
                s += __shfl_xor(s, off, 64);
                liv += __shfl_xor(liv, off, 64);
            }
            if (lane == 0) { supS[row] = s; supLi[row] = liv; }
        }
        return;
    }

    __shared__ char sm[2][8192];   // double-buffered B blocks
    const int rb = rt * 4 + w;
    const int growbase = rt * 128 + w * 32;
    short8 Ah[8];
    {
        size_t abase = (size_t)rb * 8192 + (size_t)lane * 16;
#pragma unroll
        for (int ks = 0; ks < 8; ++ks)
            Ah[ks] = *(const short8*)(Xb + abase + (size_t)ks * 1024);
    }
    int rlab[16];
#pragma unroll
    for (int reg = 0; reg < 16; ++reg) {
        int ro = (reg & 3) + 8 * (reg >> 2) + 4 * half;
        rlab[reg] = labels[growbase + ro];
    }
    float sS[16], sN[16];
#pragma unroll
    for (int reg = 0; reg < 16; ++reg) { sS[reg] = 0.f; sN[reg] = 0.f; }

    const bool isB2 = (cg < NCG2);
    const int t1 = cg - NCG2;
    if (isB2) {
        const int cb0 = cg * 8;
        stage_cb(Xb, cb0, sm[0], w, lane);
        __syncthreads();
#pragma unroll
        for (int i = 0; i < 8; ++i) {
            const int cb = cb0 + i;
            if (i < 7) stage_cb(Xb, cb + 1, sm[(i + 1) & 1], w, lane);
            int lc = labels[cb * 32 + ln];
            float c = (float)cntAll[lc];
            float rn = __builtin_amdgcn_rcpf(c);
            float drm = __builtin_amdgcn_rcpf(c - ALPHA) - rn;
            tile_lds(sm[i & 1], cb, lc, rn, drm, cb == rb,
                     lane, half, ln, growbase, Ah, rlab, sS, sN);
            __syncthreads();
        }
    } else {
        const bool isBatch = (t1 < 8);
        const int cbb = isBatch ? (t1 * 4) : CB_CENT;
        stage_cb(Xb, cbb, sm[0], w, lane);
        __syncthreads();
#pragma unroll
        for (int i = 0; i < 4; ++i) {
            const int cb = cbb + i;
            if (i < 3) stage_cb(Xb, cb + 1, sm[(i + 1) & 1], w, lane);
            const int ccol = cb * 32 + ln;
            int lc;
            if (isBatch) lc = labels[ccol];
            else { int c2 = ccol - NTOT; lc = (c2 < CC) ? c2 : -1; }
            float c1 = (float)((lc >= 0 ? cntBatch[lc] : 0) + 1);
            float rn = (lc >= 0) ? __builtin_amdgcn_rcpf(c1) : 0.f;
            float drm = (lc >= 0) ? (__builtin_amdgcn_rcpf(fmaxf(c1 - 1.f, 1.f)) - rn) : 0.f;
            tile_lds(sm[i & 1], cb, lc, rn, drm, isBatch && (cb == rb),
                     lane, half, ln, growbase, Ah, rlab, sS, sN);
            __syncthreads();
        }
    }
    float* pS = isB2 ? p2S : p1S;
    float* pN = isB2 ? p2N : p1N;
    const int slice = isB2 ? cg : t1;
#pragma unroll
    for (int reg = 0; reg < 16; ++reg) {
        float a = sS[reg], c = sN[reg];
#pragma unroll
        for (int off = 1; off < 32; off <<= 1) {
            a += __shfl_xor(a, off, 64);
            c += __shfl_xor(c, off, 64);
        }
        if (ln == 0) {
            int ro = (reg & 3) + 8 * (reg >> 2) + 4 * half;
            int grow = growbase + ro;
            pS[(size_t)slice * BB + grow] = a;
            pN[(size_t)slice * BB + grow] = c;
        }
    }
}

// ---------------- finalize: one block, 1024 threads ----------------
__global__ __launch_bounds__(1024) void finalize_k(
    const int* __restrict__ labels,
    const int* __restrict__ cntAll, const int* __restrict__ cntBatch,
    const float* __restrict__ p2S, const float* __restrict__ p2N,
    const float* __restrict__ p1S, const float* __restrict__ p1N,
    const float* __restrict__ supS, const float* __restrict__ supLi,
    float* __restrict__ out) {
    const int t = threadIdx.x;
    const int li = labels[t];
    float S2 = supS[t], N2 = 0.f;
#pragma unroll 4
    for (int c = 0; c < NCG2; ++c) {
        S2 += p2S[(size_t)c * BB + t];
        N2 += p2N[(size_t)c * BB + t];
    }
    float S1 = 0.f, N1v = 0.f;
#pragma unroll
    for (int c = 0; c < 9; ++c) {
        S1 += p1S[(size_t)c * BB + t];
        N1v += p1N[(size_t)c * BB + t];
    }
    N2 *= INV_T; N1v *= INV_T;
    float sli = supLi[t];
    float cA = (float)cntAll[li];
    float msum2 = fmaf(ALPHA, cA - 1.f, 1.f);
    float loss2 = -(fmaf(ALPHA, N2, sli) / msum2 - INV_T - logf(S2 + EPSV));
    float loss1 = -(N1v / (float)cntBatch[li] - INV_T - logf(S1 + EPSV));
    float s = loss1 + loss2;
    __shared__ float buf[16];
#pragma unroll
    for (int off = 1; off < 64; off <<= 1) s += __shfl_xor(s, off, 64);
    if ((t & 63) == 0) buf[t >> 6] = s;
    __syncthreads();
    if (t < 64) {
        float x = (t < 16) ? buf[t] : 0.f;
#pragma unroll
        for (int off = 1; off < 16; off <<= 1) x += __shfl_xor(x, off, 64);
        if (t == 0) out[0] = x / (float)BB;
    }
}

extern "C" void kernel_launch(void* const* d_in, const int* in_sizes, int n_in,
                              void* d_out, int out_size, void* d_ws, size_t ws_size,
                              hipStream_t stream) {
    const float* feats   = (const float*)d_in[0];
    const float* sup     = (const float*)d_in[1];
    const float* centers = (const float*)d_in[2];
    const int*   labels  = (const int*)d_in[3];
    float* out = (float*)d_out;
    char*  wsb = (char*)d_ws;

    const size_t X2_BYTES = (size_t)NCB * 8192;         // 8,683,520
    unsigned short* X2 = (unsigned short*)wsb;
    char* base2 = wsb + X2_BYTES;
    int* cntAll   = (int*)base2;                        // 128 ints
    int* cntBatch = cntAll + 128;                       // 128 ints
    float* p2S = (float*)(base2 + 1024);                // 132*1024
    float* p2N = p2S + (size_t)NCG2 * BB;
    float* p1S = p2N + (size_t)NCG2 * BB;               // 9*1024
    float* p1N = p1S + (size_t)9 * BB;
    float* supS  = p1N + (size_t)9 * BB;                // 1024
    float* supLi = supS + BB;                           // 1024

    hipMemsetAsync(base2, 0, 1024, stream);             // counters only
    prep_k<<<NCB + NHIST, 256, 0, stream>>>(feats, centers, labels, X2, cntAll, cntBatch);
    gemm_k<<<8 * 8 * 18, 256, 0, stream>>>(X2, labels, cntAll, cntBatch, sup,
                                           p2S, p2N, p1S, p1N, supS, supLi);
    finalize_k<<<1, 1024, 0, stream>>>(labels, cntAll, cntBatch, p2S, p2N, p1S, p1N,
                                       supS, supLi, out);
}

// Round 11
// 157.487 us; speedup vs baseline: 1.1734x; 1.0222x over previous
//
#include <hip/hip_runtime.h>
#include <math.h>

#define KQ   32768
#define CC   100
#define BB   1024
#define DD   128
#define NTOT (BB + KQ)        // 33792
#define CB_CENT 1056
#define NCB  1060             // 32-row blocks in X2
#define NHIST 33              // histogram blocks
#define NCG2 132              // branch-2 col groups (8 cb each)
#define CG_SUP 141            // sup group id (after 9 branch-1 groups)
#define NW1  1152             // branch-1 weight-table size (1124 + pad)

#define INV_T  14.285714285714286f
#define K2E    20.609929f     // INV_T * log2(e)
#define ALPHA  0.05f
#define EPSV   1e-12f

typedef __attribute__((ext_vector_type(8)))  short          short8;
typedef __attribute__((ext_vector_type(8)))  unsigned short ushort8;
typedef __attribute__((ext_vector_type(16))) float          float16;

__device__ __forceinline__ unsigned short f2bf_rne(float f) {
    unsigned int u = __float_as_uint(f);
    return (unsigned short)((u + 0x7FFFu + ((u >> 16) & 1u)) >> 16);
}

// X2 layout per 32-row block cb (8192 B): [ks 0..7][lane 0..63][16 B]
// element (row r, k): cb=r>>5, ks=k>>4, lane=(r&31)+32*((k>>3)&1), j=k&7
// == 32x32x16 MFMA A/B operand layout (verified R2-R10).

// ---------------- prep: convert+tile + parallel histogram ----------------
__global__ __launch_bounds__(256) void prep_k(const float* __restrict__ feats,
                                              const float* __restrict__ centers,
                                              const int* __restrict__ labels,
                                              unsigned short* __restrict__ X2,
                                              int* __restrict__ cntAll,
                                              int* __restrict__ cntBatch) {
    const int b = blockIdx.x, t = threadIdx.x;
    if (b >= NCB) {  // histogram: LDS-local then one global atomic per bin
        __shared__ int hA[CC], hB[CC];
        if (t < CC) { hA[t] = 0; hB[t] = 0; }
        __syncthreads();
        const int base = (b - NCB) * 1024;
#pragma unroll
        for (int q = 0; q < 4; ++q) {
            int idx = base + q * 256 + t;
            int l = labels[idx];
            atomicAdd(&hA[l], 1);
            if (idx < BB) atomicAdd(&hB[l], 1);
        }
        __syncthreads();
        if (t < CC) {
            if (hA[t]) atomicAdd(&cntAll[t], hA[t]);
            if (hB[t]) atomicAdd(&cntBatch[t], hB[t]);
        }
        return;
    }
    __shared__ unsigned short sm[8 * 66 * 8];   // stride-66 slots: conflict-free both phases
    const int rl = t >> 3, c8 = t & 7;
    const int r = b * 32 + rl;
    const float* src;
    if (r < NTOT)            src = &feats[(size_t)r * DD];
    else if (r < NTOT + CC)  src = &centers[(size_t)(r - NTOT) * DD];
    else                     src = nullptr;
#pragma unroll
    for (int s = 0; s < 2; ++s) {
        const int c8p = c8 + 8 * s;
        float v[8];
        if (src) {
            const float4* p = (const float4*)(src + c8p * 8);
            float4 q0 = p[0], q1 = p[1];
            v[0]=q0.x; v[1]=q0.y; v[2]=q0.z; v[3]=q0.w;
            v[4]=q1.x; v[5]=q1.y; v[6]=q1.z; v[7]=q1.w;
        } else {
#pragma unroll
            for (int j = 0; j < 8; ++j) v[j] = 0.f;
        }
        ushort8 H;
#pragma unroll
        for (int m = 0; m < 8; ++m) H[m] = f2bf_rne(v[m]);
        const int ks = c8p >> 1, lh = c8p & 1;
        *(ushort8*)&sm[(ks * 66 + rl + 32 * lh) * 8] = H;
    }
    __syncthreads();
    ushort8* dst = (ushort8*)((char*)X2 + (size_t)b * 8192);
#pragma unroll
    for (int j = 0; j < 2; ++j) {
        const int idx = j * 256 + t;
        const int ks = idx >> 6, ln = idx & 63;
        dst[idx] = *(const ushort8*)&sm[(ks * 66 + ln) * 8];
    }
}

// ---------------- wcalc: precompute per-column softmax weights ----------------
// grid 137: b<132 -> branch-2 cols; b>=132 -> branch-1 cols (incl centers, pad)
__global__ __launch_bounds__(256) void wcalc_k(const int* __restrict__ labels,
                                               const int* __restrict__ cntAll,
                                               const int* __restrict__ cntBatch,
                                               float* __restrict__ colRn,
                                               float* __restrict__ colDrm,
                                               int* __restrict__ colLab1,
                                               float* __restrict__ colRn1,
                                               float* __restrict__ colDrm1) {
    const int b = blockIdx.x, t = threadIdx.x;
    if (b < 132) {
        const int idx = b * 256 + t;
        int lab = labels[idx];
        float c = (float)cntAll[lab];
        float rn = __builtin_amdgcn_rcpf(c);
        colRn[idx] = rn;
        colDrm[idx] = __builtin_amdgcn_rcpf(c - ALPHA) - rn;
    } else {
        const int j = (b - 132) * 256 + t;
        if (j >= NW1) return;
        int lab;
        if (j < BB)            lab = labels[j];
        else if (j < BB + CC)  lab = j - BB;
        else                   lab = -1;
        float rn = 0.f, drm = 0.f;
        if (lab >= 0) {
            float c1 = (float)(cntBatch[lab] + 1);
            rn = __builtin_amdgcn_rcpf(c1);
            drm = __builtin_amdgcn_rcpf(fmaxf(c1 - 1.f, 1.f)) - rn;
        }
        colLab1[j] = lab; colRn1[j] = rn; colDrm1[j] = drm;
    }
}

// ---------------- epilogue for one 32x32 tile ----------------
__device__ __forceinline__ void epi_tile(
    const float16& acc, int cb, int lc, float rn, float drm, bool checkDiag,
    int half, int ln, int growbase, const int* rlab, float* sS, float* sN)
{
    const int ccol = cb * 32 + ln;
#pragma unroll
    for (int reg = 0; reg < 16; ++reg) {
        int ro = (reg & 3) + 8 * (reg >> 2) + 4 * half;
        float a  = acc[reg];
        float mf = (lc == rlab[reg]) ? 1.f : 0.f;
        float wgt = fmaf(mf, drm, rn);
        if (checkDiag) {                 // wave-uniform
            bool d = (ccol == growbase + ro);
            wgt = d ? 0.f : wgt;
            mf  = d ? 0.f : mf;
        }
        float e = exp2f(fmaf(a, K2E, -K2E));
        sS[reg] = fmaf(e, wgt, sS[reg]);
        sN[reg] = fmaf(mf, a, sN[reg]);  // un-scaled dot; *INV_T at finalize
    }
}

// ---------------- dual-stream pair of 32x32 tiles (R8/R9 proven inner shape) ----------------
__device__ __forceinline__ void pair_tiles(
    const char* Xb, int cb0, int cb1,
    int lc0, float rn0, float drm0, bool dg0,
    int lc1, float rn1, float drm1, bool dg1,
    int lane, int half, int ln, int growbase,
    const short8* Ah, const int* rlab, float* sS, float* sN)
{
    const size_t b0 = (size_t)cb0 * 8192 + (size_t)lane * 16;
    const size_t b1 = (size_t)cb1 * 8192 + (size_t)lane * 16;
    float16 a0, a1;
#pragma unroll
    for (int reg = 0; reg < 16; ++reg) { a0[reg] = 0.f; a1[reg] = 0.f; }
#pragma unroll
    for (int ks = 0; ks < 8; ++ks) {
        short8 B0 = *(const short8*)(Xb + b0 + (size_t)ks * 1024);
        short8 B1 = *(const short8*)(Xb + b1 + (size_t)ks * 1024);
        a0 = __builtin_amdgcn_mfma_f32_32x32x16_bf16(Ah[ks], B0, a0, 0, 0, 0);
        a1 = __builtin_amdgcn_mfma_f32_32x32x16_bf16(Ah[ks], B1, a1, 0, 0, 0);
    }
    epi_tile(a0, cb0, lc0, rn0, drm0, dg0, half, ln, growbase, rlab, sS, sN);
    epi_tile(a1, cb1, lc1, rn1, drm1, dg1, half, ln, growbase, rlab, sS, sN);
}

// ---------------- fused GEMM (b2 + b1) + sup-sums, XCD-swizzled 1-D grid ----------------
// grid 1152 = 8 xcd * 8 rt * 18 ci; cg = xcd + 8*ci.
// cg<132: branch2 (8 cb). 132..140: branch1 (4 cb). 141: sup sums. >141: idle.
__global__ __launch_bounds__(256) void gemm_k(
    const unsigned short* __restrict__ X2, const int* __restrict__ labels,
    const int* __restrict__ cntAll,
    const float* __restrict__ colRn, const float* __restrict__ colDrm,
    const int* __restrict__ colLab1,
    const float* __restrict__ colRn1, const float* __restrict__ colDrm1,
    const float* __restrict__ sup,
    float* __restrict__ acc4, float* __restrict__ aLi) {
    const int b = blockIdx.x;
    const int xcd = b & 7, l = b >> 3;
    const int rt = l & 7, ci = l >> 3;
    const int cg = xcd + 8 * ci;
    if (cg > CG_SUP) return;

    const int tid = threadIdx.x;
    const int lane = tid & 63, w = tid >> 6;
    const int half = lane >> 5, ln = lane & 31;
    const char* Xb = (const char*)X2;

    if (cg == CG_SUP) {  // sup-logits exp-sums, coalesced (lane = class), wave = 32 rows
        const int g = rt * 4 + w;
        const int c0 = lane, c1 = lane + 64;
        float n0 = (float)cntAll[c0];
        float rA0 = __builtin_amdgcn_rcpf(n0);
        float rAm0 = __builtin_amdgcn_rcpf(fmaxf(n0 - 1.f, 1.f));
        float rA1 = 0.f, rAm1 = 0.f;
        if (lane < 36) {
            float n1 = (float)cntAll[c1];
            rA1 = __builtin_amdgcn_rcpf(n1);
            rAm1 = __builtin_amdgcn_rcpf(fmaxf(n1 - 1.f, 1.f));
        }
        for (int rr = 0; rr < 32; ++rr) {
            int row = g * 32 + rr;
            int li = labels[row];
            const float* srow = &sup[(size_t)row * CC];
            float v0 = srow[c0];
            float s = __expf(v0 - INV_T) * ((c0 == li) ? rAm0 : rA0);
            float liv = (c0 == li) ? v0 : 0.f;
            if (lane < 36) {
                float v1 = srow[c1];
                s += __expf(v1 - INV_T) * ((c1 == li) ? rAm1 : rA1);
                liv += (c1 == li) ? v1 : 0.f;
            }
#pragma unroll
            for (int off = 1; off < 64; off <<= 1) {
                s += __shfl_xor(s, off, 64);
                liv += __shfl_xor(liv, off, 64);
            }
            if (lane == 0) {
                atomicAdd(&acc4[row], s);
                atomicAdd(&aLi[row], liv);
            }
        }
        return;
    }

    const int rb = rt * 4 + w;
    const int growbase = rt * 128 + w * 32;
    short8 Ah[8];
    {
        size_t abase = (size_t)rb * 8192 + (size_t)lane * 16;
#pragma unroll
        for (int ks = 0; ks < 8; ++ks)
            Ah[ks] = *(const short8*)(Xb + abase + (size_t)ks * 1024);
    }
    int rlab[16];
#pragma unroll
    for (int reg = 0; reg < 16; ++reg) {
        int ro = (reg & 3) + 8 * (reg >> 2) + 4 * half;
        rlab[reg] = labels[growbase + ro];
    }
    float sS[16], sN[16];
#pragma unroll
    for (int reg = 0; reg < 16; ++reg) { sS[reg] = 0.f; sN[reg] = 0.f; }

    const bool isB2 = (cg < NCG2);
    const int t1 = cg - NCG2;
    if (isB2) {
#pragma unroll
        for (int p = 0; p < 4; ++p) {
            const int cb0 = cg * 8 + 2 * p, cb1 = cb0 + 1;
            const int wc0 = cb0 * 32 + ln, wc1 = cb1 * 32 + ln;
            // independent, coalesced loads (no dependent gather)
            int lc0 = labels[wc0], lc1 = labels[wc1];
            float rn0 = colRn[wc0], rn1 = colRn[wc1];
            float drm0 = colDrm[wc0], drm1 = colDrm[wc1];
            pair_tiles(Xb, cb0, cb1, lc0, rn0, drm0, cb0 == rb,
                       lc1, rn1, drm1, cb1 == rb,
                       lane, half, ln, growbase, Ah, rlab, sS, sN);
        }
    } else {
        const bool isBatch = (t1 < 8);
#pragma unroll
        for (int p = 0; p < 2; ++p) {
            int cb0, cb1, wc0, wc1;
            if (isBatch) {
                cb0 = t1 * 4 + 2 * p; cb1 = cb0 + 1;
                wc0 = cb0 * 32 + ln; wc1 = cb1 * 32 + ln;
            } else {
                cb0 = CB_CENT + 2 * p; cb1 = cb0 + 1;
                wc0 = 1024 + (cb0 - CB_CENT) * 32 + ln; wc1 = wc0 + 32;
            }
            int lc0 = colLab1[wc0], lc1 = colLab1[wc1];
            float rn0 = colRn1[wc0], rn1 = colRn1[wc1];
            float drm0 = colDrm1[wc0], drm1 = colDrm1[wc1];
            pair_tiles(Xb, cb0, cb1, lc0, rn0, drm0, isBatch && (cb0 == rb),
                       lc1, rn1, drm1, isBatch && (cb1 == rb),
                       lane, half, ln, growbase, Ah, rlab, sS, sN);
        }
    }
    float* aS = isB2 ? acc4          : (acc4 + 2048);
    float* aN = isB2 ? (acc4 + 1024) : (acc4 + 3072);
#pragma unroll
    for (int reg = 0; reg < 16; ++reg) {
        float a = sS[reg], c = sN[reg];
#pragma unroll
        for (int off = 1; off < 32; off <<= 1) {
            a += __shfl_xor(a, off, 64);
            c += __shfl_xor(c, off, 64);
        }
        if (ln == 0) {
            int ro = (reg & 3) + 8 * (reg >> 2) + 4 * half;
            int grow = growbase + ro;
            atomicAdd(&aS[grow], a);
            atomicAdd(&aN[grow], c);
        }
    }
}

// ---------------- finalize: one block, 1024 threads, trivial ----------------
__global__ __launch_bounds__(1024) void finalize_k(
    const int* __restrict__ labels,
    const int* __restrict__ cntAll, const int* __restrict__ cntBatch,
    const float* __restrict__ acc4, const float* __restrict__ aLi,
    float* __restrict__ out) {
    const int t = threadIdx.x;
    const int li = labels[t];
    float S2 = acc4[t];
    float N2 = acc4[1024 + t] * INV_T;
    float S1 = acc4[2048 + t];
    float N1v = acc4[3072 + t] * INV_T;
    float sli = aLi[t];
    float cA = (float)cntAll[li];
    float msum2 = fmaf(ALPHA, cA - 1.f, 1.f);
    float loss2 = -(fmaf(ALPHA, N2, sli) / msum2 - INV_T - logf(S2 + EPSV));
    float loss1 = -(N1v / (float)cntBatch[li] - INV_T - logf(S1 + EPSV));
    float s = loss1 + loss2;
    __shared__ float buf[16];
#pragma unroll
    for (int off = 1; off < 64; off <<= 1) s += __shfl_xor(s, off, 64);
    if ((t & 63) == 0) buf[t >> 6] = s;
    __syncthreads();
    if (t < 64) {
        float x = (t < 16) ? buf[t] : 0.f;
#pragma unroll
        for (int off = 1; off < 16; off <<= 1) x += __shfl_xor(x, off, 64);
        if (t == 0) out[0] = x / (float)BB;
    }
}

extern "C" void kernel_launch(void* const* d_in, const int* in_sizes, int n_in,
                              void* d_out, int out_size, void* d_ws, size_t ws_size,
                              hipStream_t stream) {
    const float* feats   = (const float*)d_in[0];
    const float* sup     = (const float*)d_in[1];
    const float* centers = (const float*)d_in[2];
    const int*   labels  = (const int*)d_in[3];
    float* out = (float*)d_out;
    char*  wsb = (char*)d_ws;

    const size_t X2_BYTES = (size_t)NCB * 8192;         // 8,683,520
    unsigned short* X2 = (unsigned short*)wsb;
    char* base2 = wsb + X2_BYTES;
    int* cntAll   = (int*)base2;                        // 128 ints
    int* cntBatch = cntAll + 128;                       // 128 ints
    float* acc4   = (float*)(base2 + 1024);             // 4*1024: S2,N2,S1,N1
    float* aLi    = acc4 + 4096;                        // 1024
    float* colRn  = aLi + 1024;                         // 33792
    float* colDrm = colRn + NTOT;                       // 33792
    int*   colLab1 = (int*)(colDrm + NTOT);             // 1152
    float* colRn1  = (float*)(colLab1 + NW1);           // 1152
    float* colDrm1 = colRn1 + NW1;                      // 1152

    hipMemsetAsync(base2, 0, 1024 + 16384 + 4096, stream);  // counters + acc4 + aLi
    prep_k<<<NCB + NHIST, 256, 0, stream>>>(feats, centers, labels, X2, cntAll, cntBatch);
    wcalc_k<<<132 + 5, 256, 0, stream>>>(labels, cntAll, cntBatch,
                                         colRn, colDrm, colLab1, colRn1, colDrm1);
    gemm_k<<<8 * 8 * 18, 256, 0, stream>>>(X2, labels, cntAll,
                                           colRn, colDrm, colLab1, colRn1, colDrm1,
                                           sup, acc4, aLi);
    finalize_k<<<1, 1024, 0, stream>>>(labels, cntAll, cntBatch, acc4, aLi, out);
}

// Round 12
// 136.707 us; speedup vs baseline: 1.3518x; 1.1520x over previous
//
#include <hip/hip_runtime.h>
#include <math.h>

#define KQ   32768
#define CC   100
#define BB   1024
#define DD   128
#define NTOT (BB + KQ)        // 33792
#define CB_CENT 1056
#define NCB  1060             // 32-row blocks in X2
#define NHIST 33              // histogram partial blocks
#define NCG2 132              // branch-2 col groups (8 cb each)
#define CG_SUP 141            // sup group id
#define NSL  141              // partial-sum slices (132 b2 + 9 b1)

#define INV_T  14.285714285714286f
#define K2E    20.609929f     // INV_T * log2(e)
#define ALPHA  0.05f
#define EPSV   1e-12f

typedef __attribute__((ext_vector_type(8)))  short          short8;
typedef __attribute__((ext_vector_type(8)))  unsigned short ushort8;
typedef __attribute__((ext_vector_type(16))) float          float16;

__device__ __forceinline__ unsigned short f2bf_rne(float f) {
    unsigned int u = __float_as_uint(f);
    return (unsigned short)((u + 0x7FFFu + ((u >> 16) & 1u)) >> 16);
}

// X2 layout per 32-row block cb (8192 B): [ks 0..7][lane 0..63][16 B]
// element (row r, k): cb=r>>5, ks=k>>4, lane=(r&31)+32*((k>>3)&1), j=k&7
// == 32x32x16 MFMA A/B operand layout (verified R2-R11).

// ---------------- prep: convert+tile + partial histograms (no global atomics) ----------------
__global__ __launch_bounds__(256) void prep_k(const float* __restrict__ feats,
                                              const float* __restrict__ centers,
                                              const int* __restrict__ labels,
                                              unsigned short* __restrict__ X2,
                                              int* __restrict__ cntP,
                                              int* __restrict__ cntB) {
    const int b = blockIdx.x, t = threadIdx.x;
    if (b >= NCB) {  // histogram partials: each block owns its own 128-int slice
        const int h = b - NCB;
        __shared__ int hA[CC], hB[CC];
        if (t < CC) { hA[t] = 0; hB[t] = 0; }
        __syncthreads();
        const int base = h * 1024;
#pragma unroll
        for (int q = 0; q < 4; ++q) {
            int l = labels[base + q * 256 + t];
            atomicAdd(&hA[l], 1);
            if (h == 0) atomicAdd(&hB[l], 1);   // batch rows are exactly block 0's range
        }
        __syncthreads();
        if (t < 128) {
            cntP[h * 128 + t] = (t < CC) ? hA[t] : 0;
            if (h == 0) cntB[t] = (t < CC) ? hB[t] : 0;
        }
        return;
    }
    __shared__ unsigned short sm[8 * 66 * 8];   // stride-66 slots
    const int rl = t >> 3, c8 = t & 7;
    const int r = b * 32 + rl;
    const float* src;
    if (r < NTOT)            src = &feats[(size_t)r * DD];
    else if (r < NTOT + CC)  src = &centers[(size_t)(r - NTOT) * DD];
    else                     src = nullptr;
#pragma unroll
    for (int s = 0; s < 2; ++s) {
        const int c8p = c8 + 8 * s;
        float v[8];
        if (src) {
            const float4* p = (const float4*)(src + c8p * 8);
            float4 q0 = p[0], q1 = p[1];
            v[0]=q0.x; v[1]=q0.y; v[2]=q0.z; v[3]=q0.w;
            v[4]=q1.x; v[5]=q1.y; v[6]=q1.z; v[7]=q1.w;
        } else {
#pragma unroll
            for (int j = 0; j < 8; ++j) v[j] = 0.f;
        }
        ushort8 H;
#pragma unroll
        for (int m = 0; m < 8; ++m) H[m] = f2bf_rne(v[m]);
        const int ks = c8p >> 1, lh = c8p & 1;
        *(ushort8*)&sm[(ks * 66 + rl + 32 * lh) * 8] = H;
    }
    __syncthreads();
    ushort8* dst = (ushort8*)((char*)X2 + (size_t)b * 8192);
#pragma unroll
    for (int j = 0; j < 2; ++j) {
        const int idx = j * 256 + t;
        const int ks = idx >> 6, ln = idx & 63;
        dst[idx] = *(const ushort8*)&sm[(ks * 66 + ln) * 8];
    }
}

// ---------------- epilogue for one 32x32 tile ----------------
__device__ __forceinline__ void epi_tile(
    const float16& acc, int cb, int lc, float rn, float drm, bool checkDiag,
    int half, int ln, int growbase, const int* rlab, float* sS, float* sN)
{
    const int ccol = cb * 32 + ln;
#pragma unroll
    for (int reg = 0; reg < 16; ++reg) {
        int ro = (reg & 3) + 8 * (reg >> 2) + 4 * half;
        float a  = acc[reg];
        float mf = (lc == rlab[reg]) ? 1.f : 0.f;
        float wgt = fmaf(mf, drm, rn);
        if (checkDiag) {                 // wave-uniform
            bool d = (ccol == growbase + ro);
            wgt = d ? 0.f : wgt;
            mf  = d ? 0.f : mf;
        }
        float e = exp2f(fmaf(a, K2E, -K2E));
        sS[reg] = fmaf(e, wgt, sS[reg]);
        sN[reg] = fmaf(mf, a, sN[reg]);  // un-scaled dot; *INV_T at finalize
    }
}

// ---------------- dual-stream pair of 32x32 tiles (R8/R9 proven inner shape) ----------------
__device__ __forceinline__ void pair_tiles(
    const char* Xb, int cb0, int cb1,
    int lc0, float rn0, float drm0, bool dg0,
    int lc1, float rn1, float drm1, bool dg1,
    int lane, int half, int ln, int growbase,
    const short8* Ah, const int* rlab, float* sS, float* sN)
{
    const size_t b0 = (size_t)cb0 * 8192 + (size_t)lane * 16;
    const size_t b1 = (size_t)cb1 * 8192 + (size_t)lane * 16;
    float16 a0, a1;
#pragma unroll
    for (int reg = 0; reg < 16; ++reg) { a0[reg] = 0.f; a1[reg] = 0.f; }
#pragma unroll
    for (int ks = 0; ks < 8; ++ks) {
        short8 B0 = *(const short8*)(Xb + b0 + (size_t)ks * 1024);
        short8 B1 = *(const short8*)(Xb + b1 + (size_t)ks * 1024);
        a0 = __builtin_amdgcn_mfma_f32_32x32x16_bf16(Ah[ks], B0, a0, 0, 0, 0);
        a1 = __builtin_amdgcn_mfma_f32_32x32x16_bf16(Ah[ks], B1, a1, 0, 0, 0);
    }
    epi_tile(a0, cb0, lc0, rn0, drm0, dg0, half, ln, growbase, rlab, sS, sN);
    epi_tile(a1, cb1, lc1, rn1, drm1, dg1, half, ln, growbase, rlab, sS, sN);
}

// ---------------- fused GEMM (b2 + b1) + sup-sums; LDS weight table; store epilogue ----------
// grid 1152 = 8 xcd * 8 rt * 18 ci; cg = xcd + 8*ci.
// cg<132: branch2 (8 cb). 132..140: branch1 (4 cb). 141: sup sums. >141: idle.
__global__ __launch_bounds__(256) void gemm_k(
    const unsigned short* __restrict__ X2, const int* __restrict__ labels,
    const int* __restrict__ cntP, const int* __restrict__ cntB,
    const float* __restrict__ sup,
    float* __restrict__ pS, float* __restrict__ pN,
    float* __restrict__ supS, float* __restrict__ supLi) {
    const int b = blockIdx.x;
    const int xcd = b & 7, l = b >> 3;
    const int rt = l & 7, ci = l >> 3;
    const int cg = xcd + 8 * ci;
    if (cg > CG_SUP) return;

    const int tid = threadIdx.x;
    const int lane = tid & 63, w = tid >> 6;
    const int half = lane >> 5, ln = lane & 31;
    const char* Xb = (const char*)X2;

    // block-local weight tables from histogram partials (no cross-block ordering)
    __shared__ float cntAF[128], rnA[128], drmA[128], rn1S[128], drm1S[128];
    if (tid < 128) {
        int s = 0;
#pragma unroll
        for (int h = 0; h < NHIST; ++h) s += cntP[h * 128 + tid];
        float cf = (float)s;
        cntAF[tid] = cf;
        float rn = __builtin_amdgcn_rcpf(fmaxf(cf, 1.f));
        rnA[tid] = (s > 0) ? __builtin_amdgcn_rcpf(cf) : 0.f;
        drmA[tid] = (s > 0) ? (__builtin_amdgcn_rcpf(cf - ALPHA) - rnA[tid]) : 0.f;
        (void)rn;
        int sb = cntB[tid];
        float c1 = (float)(sb + 1);
        float rn1 = __builtin_amdgcn_rcpf(c1);
        rn1S[tid] = rn1;
        drm1S[tid] = __builtin_amdgcn_rcpf(fmaxf(c1 - 1.f, 1.f)) - rn1;
    }
    __syncthreads();

    if (cg == CG_SUP) {  // sup-logits exp-sums, coalesced (lane = class), wave = 32 rows
        const int g = rt * 4 + w;
        const int c0 = lane, c1 = lane + 64;
        float n0 = cntAF[c0];
        float rA0 = __builtin_amdgcn_rcpf(n0);
        float rAm0 = __builtin_amdgcn_rcpf(fmaxf(n0 - 1.f, 1.f));
        float rA1 = 0.f, rAm1 = 0.f;
        if (lane < 36) {
            float n1 = cntAF[c1];
            rA1 = __builtin_amdgcn_rcpf(n1);
            rAm1 = __builtin_amdgcn_rcpf(fmaxf(n1 - 1.f, 1.f));
        }
        for (int rr = 0; rr < 32; ++rr) {
            int row = g * 32 + rr;
            int li = labels[row];
            const float* srow = &sup[(size_t)row * CC];
            float v0 = srow[c0];
            float s = __expf(v0 - INV_T) * ((c0 == li) ? rAm0 : rA0);
            float liv = (c0 == li) ? v0 : 0.f;
            if (lane < 36) {
                float v1 = srow[c1];
                s += __expf(v1 - INV_T) * ((c1 == li) ? rAm1 : rA1);
                liv += (c1 == li) ? v1 : 0.f;
            }
#pragma unroll
            for (int off = 1; off < 64; off <<= 1) {
                s += __shfl_xor(s, off, 64);
                liv += __shfl_xor(liv, off, 64);
            }
            if (lane == 0) { supS[row] = s; supLi[row] = liv; }
        }
        return;
    }

    const int rb = rt * 4 + w;
    const int growbase = rt * 128 + w * 32;
    short8 Ah[8];
    {
        size_t abase = (size_t)rb * 8192 + (size_t)lane * 16;
#pragma unroll
        for (int ks = 0; ks < 8; ++ks)
            Ah[ks] = *(const short8*)(Xb + abase + (size_t)ks * 1024);
    }
    int rlab[16];
#pragma unroll
    for (int reg = 0; reg < 16; ++reg) {
        int ro = (reg & 3) + 8 * (reg >> 2) + 4 * half;
        rlab[reg] = labels[growbase + ro];
    }
    float sS[16], sN[16];
#pragma unroll
    for (int reg = 0; reg < 16; ++reg) { sS[reg] = 0.f; sN[reg] = 0.f; }

    const bool isB2 = (cg < NCG2);
    const int t1 = cg - NCG2;
    if (isB2) {
#pragma unroll
        for (int p = 0; p < 4; ++p) {
            const int cb0 = cg * 8 + 2 * p, cb1 = cb0 + 1;
            int lc0 = labels[cb0 * 32 + ln];
            int lc1 = labels[cb1 * 32 + ln];
            float rn0 = rnA[lc0], drm0 = drmA[lc0];
            float rn1 = rnA[lc1], drm1 = drmA[lc1];
            pair_tiles(Xb, cb0, cb1, lc0, rn0, drm0, cb0 == rb,
                       lc1, rn1, drm1, cb1 == rb,
                       lane, half, ln, growbase, Ah, rlab, sS, sN);
        }
    } else {
        const bool isBatch = (t1 < 8);
#pragma unroll
        for (int p = 0; p < 2; ++p) {
            int cb0, cb1, lc0, lc1;
            if (isBatch) {
                cb0 = t1 * 4 + 2 * p; cb1 = cb0 + 1;
                lc0 = labels[cb0 * 32 + ln];
                lc1 = labels[cb1 * 32 + ln];
            } else {
                cb0 = CB_CENT + 2 * p; cb1 = cb0 + 1;
                int q0 = cb0 * 32 + ln - NTOT, q1 = cb1 * 32 + ln - NTOT;
                lc0 = (q0 < CC) ? q0 : -1;
                lc1 = (q1 < CC) ? q1 : -1;
            }
            float rn0 = (lc0 >= 0) ? rn1S[lc0] : 0.f;
            float drm0 = (lc0 >= 0) ? drm1S[lc0] : 0.f;
            float rn1 = (lc1 >= 0) ? rn1S[lc1] : 0.f;
            float drm1 = (lc1 >= 0) ? drm1S[lc1] : 0.f;
            pair_tiles(Xb, cb0, cb1, lc0, rn0, drm0, isBatch && (cb0 == rb),
                       lc1, rn1, drm1, isBatch && (cb1 == rb),
                       lane, half, ln, growbase, Ah, rlab, sS, sN);
        }
    }
    const int slice = isB2 ? cg : (NCG2 + t1);
#pragma unroll
    for (int reg = 0; reg < 16; ++reg) {
        float a = sS[reg], c = sN[reg];
#pragma unroll
        for (int off = 1; off < 32; off <<= 1) {
            a += __shfl_xor(a, off, 64);
            c += __shfl_xor(c, off, 64);
        }
        if (ln == 0) {
            int ro = (reg & 3) + 8 * (reg >> 2) + 4 * half;
            int grow = growbase + ro;
            pS[(size_t)slice * BB + grow] = a;
            pN[(size_t)slice * BB + grow] = c;
        }
    }
}

// ---------------- finalize: one block, 1024 threads ----------------
__global__ __launch_bounds__(1024) void finalize_k(
    const int* __restrict__ labels,
    const int* __restrict__ cntP, const int* __restrict__ cntB,
    const float* __restrict__ pS, const float* __restrict__ pN,
    const float* __restrict__ supS, const float* __restrict__ supLi,
    float* __restrict__ out) {
    const int t = threadIdx.x;
    __shared__ float cntA[128];
    if (t < 128) {
        int s = 0;
#pragma unroll
        for (int h = 0; h < NHIST; ++h) s += cntP[h * 128 + t];
        cntA[t] = (float)s;
    }
    __syncthreads();
    const int li = labels[t];
    float S2 = supS[t], N2 = 0.f;
#pragma unroll 4
    for (int c = 0; c < NCG2; ++c) {
        S2 += pS[(size_t)c * BB + t];
        N2 += pN[(size_t)c * BB + t];
    }
    float S1 = 0.f, N1v = 0.f;
#pragma unroll
    for (int c = NCG2; c < NSL; ++c) {
        S1 += pS[(size_t)c * BB + t];
        N1v += pN[(size_t)c * BB + t];
    }
    N2 *= INV_T; N1v *= INV_T;
    float sli = supLi[t];
    float cA = cntA[li];
    float msum2 = fmaf(ALPHA, cA - 1.f, 1.f);
    float loss2 = -(fmaf(ALPHA, N2, sli) / msum2 - INV_T - logf(S2 + EPSV));
    float loss1 = -(N1v / (float)cntB[li] - INV_T - logf(S1 + EPSV));
    float s = loss1 + loss2;
    __shared__ float buf[16];
#pragma unroll
    for (int off = 1; off < 64; off <<= 1) s += __shfl_xor(s, off, 64);
    if ((t & 63) == 0) buf[t >> 6] = s;
    __syncthreads();
    if (t < 64) {
        float x = (t < 16) ? buf[t] : 0.f;
#pragma unroll
        for (int off = 1; off < 16; off <<= 1) x += __shfl_xor(x, off, 64);
        if (t == 0) out[0] = x / (float)BB;
    }
}

extern "C" void kernel_launch(void* const* d_in, const int* in_sizes, int n_in,
                              void* d_out, int out_size, void* d_ws, size_t ws_size,
                              hipStream_t stream) {
    const float* feats   = (const float*)d_in[0];
    const float* sup     = (const float*)d_in[1];
    const float* centers = (const float*)d_in[2];
    const int*   labels  = (const int*)d_in[3];
    float* out = (float*)d_out;
    char*  wsb = (char*)d_ws;

    const size_t X2_BYTES = (size_t)NCB * 8192;         // 8,683,520
    unsigned short* X2 = (unsigned short*)wsb;
    char* base2 = wsb + X2_BYTES;
    int* cntP = (int*)base2;                            // 33*128 ints (partial hists)
    int* cntB = cntP + NHIST * 128;                     // 128 ints
    float* pS = (float*)(cntB + 128);                   // 141*1024
    float* pN = pS + (size_t)NSL * BB;                  // 141*1024
    float* supS  = pN + (size_t)NSL * BB;               // 1024
    float* supLi = supS + BB;                           // 1024

    // no memsets: every workspace word is written before it is read
    prep_k<<<NCB + NHIST, 256, 0, stream>>>(feats, centers, labels, X2, cntP, cntB);
    gemm_k<<<8 * 8 * 18, 256, 0, stream>>>(X2, labels, cntP, cntB, sup,
                                           pS, pN, supS, supLi);
    finalize_k<<<1, 1024, 0, stream>>>(labels, cntP, cntB, pS, pN, supS, supLi, out);
}